// Round 1
// baseline (360.895 us; speedup 1.0000x reference)
//
#include <hip/hip_runtime.h>
#include <hip/hip_bf16.h>
#include <stdint.h>

#define DI __device__ __forceinline__

constexpr int Bn = 64;               // batch
constexpr int S  = 197;              // seq
constexpr int Dm = 768;              // model dim
constexpr int H  = 12;               // heads
constexpr int DH = 64;               // head dim
constexpr int M  = Bn * S;           // 12608 rows
constexpr int SP = 224;              // padded seq for transposed V (7 * 32)
constexpr int MD = M * Dm;           // 9,682,944
constexpr int WN = Dm * Dm;          // 589,824

typedef __attribute__((ext_vector_type(8))) short bf8;   // 8 bf16 = 4 VGPRs
typedef __attribute__((ext_vector_type(4))) float f4;

DI ushort f2bf(float f) {
  union { __hip_bfloat16 b; ushort u; } cv;
  cv.b = __float2bfloat16(f);
  return cv.u;
}

// async global->LDS, 16B per lane; lds base must be wave-uniform
DI void gload_lds16(const void* g, const void* lds) {
  __builtin_amdgcn_global_load_lds(
      (__attribute__((address_space(1))) void*)(uintptr_t)g,
      (__attribute__((address_space(3))) void*)(uint32_t)(uintptr_t)lds,
      16, 0, 0);
}

DI bf8 ld16(const ushort* p) { return *(const bf8*)p; }

// ---------------------------------------------------------------- convert
__global__ __launch_bounds__(256) void convert_all(
    const float4* __restrict__ q,  const float4* __restrict__ k,
    const float4* __restrict__ v,  const float4* __restrict__ wq,
    const float4* __restrict__ wk, const float4* __restrict__ wv,
    const float4* __restrict__ wo,
    ushort4* __restrict__ qb, ushort4* __restrict__ kb,
    ushort4* __restrict__ vb, ushort4* __restrict__ wb) {
  constexpr int NT = MD / 4;   // 2,420,736 vec4 per activation tensor
  constexpr int NW = WN / 4;   // 147,456 vec4 per weight
  int i = blockIdx.x * 256 + threadIdx.x;     // grid sized exactly
  const float4* src; ushort4* dst; int off;
  if (i < NT)            { src = q; dst = qb; off = i; }
  else if (i < 2 * NT)   { src = k; dst = kb; off = i - NT; }
  else if (i < 3 * NT)   { src = v; dst = vb; off = i - 2 * NT; }
  else {
    int j = i - 3 * NT;
    int wsel = j / NW; off = j - wsel * NW;
    src = wsel == 0 ? wq : wsel == 1 ? wk : wsel == 2 ? wv : wo;
    dst = wb + (size_t)wsel * NW;
  }
  float4 f = src[off];
  ushort4 u;
  u.x = f2bf(f.x); u.y = f2bf(f.y); u.z = f2bf(f.z); u.w = f2bf(f.w);
  dst[off] = u;
}

// ---------------------------------------------------------------- GEMM C = A * W^T
// A: [M x 768] bf16 row-major, W: [768 x 768] bf16 row-major ([out][in]).
// MODE 0: batched z in {0,1,2} -> Qh/Kh [B,H,S,DH] bf16, z==2 -> Vt [B,H,DH,SP] bf16
// MODE 1: fp32 row-major store to OF [M x 768]
template <int MODE>
__global__ __launch_bounds__(256) void gemm_bt(
    const ushort* __restrict__ Abase, const ushort* __restrict__ Wbase,
    ushort* __restrict__ OQK, ushort* __restrict__ OV, float* __restrict__ OF) {
  __shared__ __align__(16) ushort As[128 * 32];
  __shared__ __align__(16) ushort Ws[128 * 32];
  const int tid  = threadIdx.x;
  const int lane = tid & 63;
  const int w    = tid >> 6;
  const int wr   = w >> 1, wc = w & 1;
  const int rsel = lane & 15, g = lane >> 4;
  const int m0 = blockIdx.x * 128, n0 = blockIdx.y * 128;
  const int z  = blockIdx.z;
  const ushort* A = Abase + (MODE == 0 ? (size_t)z * MD : 0);
  const ushort* W = Wbase + (MODE == 0 ? (size_t)z * WN : 0);

  const f4 fz = {0.f, 0.f, 0.f, 0.f};
  f4 acc[4][4];
#pragma unroll
  for (int i = 0; i < 4; i++)
#pragma unroll
    for (int j = 0; j < 4; j++) acc[i][j] = fz;

  // staging: 512 chunks of 16B per 128x32 tile; chunk c -> row c>>2, kofs (c&3)*8
  const int row0 = tid >> 2,        ko0 = (tid & 3) * 8;
  const int row1 = 64 + (tid >> 2), ko1 = ko0;
  int ar0 = m0 + row0; if (ar0 >= M) ar0 = M - 1;
  int ar1 = m0 + row1; if (ar1 >= M) ar1 = M - 1;
  const int wbase = (tid & ~63) * 8;   // ushort offset of this wave's chunk base

  for (int k0 = 0; k0 < Dm; k0 += 32) {
    gload_lds16(A + (size_t)ar0 * Dm + k0 + ko0, As + wbase);
    gload_lds16(A + (size_t)ar1 * Dm + k0 + ko1, As + 2048 + wbase);
    gload_lds16(W + (size_t)(n0 + row0) * Dm + k0 + ko0, Ws + wbase);
    gload_lds16(W + (size_t)(n0 + row1) * Dm + k0 + ko1, Ws + 2048 + wbase);
    __syncthreads();
    bf8 af[4], wf[4];
#pragma unroll
    for (int i = 0; i < 4; i++)
      af[i] = ld16(&As[(wr * 64 + i * 16 + rsel) * 32 + g * 8]);
#pragma unroll
    for (int j = 0; j < 4; j++)
      wf[j] = ld16(&Ws[(wc * 64 + j * 16 + rsel) * 32 + g * 8]);
#pragma unroll
    for (int i = 0; i < 4; i++)
#pragma unroll
      for (int j = 0; j < 4; j++)
        acc[i][j] = __builtin_amdgcn_mfma_f32_16x16x32_bf16(af[i], wf[j], acc[i][j], 0, 0, 0);
    __syncthreads();
  }

  // epilogue: C row = (lane>>4)*4+reg (m), col = lane&15 (n)
#pragma unroll
  for (int i = 0; i < 4; i++) {
    const int mb = m0 + wr * 64 + i * 16 + g * 4;
#pragma unroll
    for (int j = 0; j < 4; j++) {
      const int n = n0 + wc * 64 + j * 16 + rsel;
#pragma unroll
      for (int rg = 0; rg < 4; rg++) {
        const int m = mb + rg;
        if (m < M) {
          const float val = acc[i][j][rg];
          if (MODE == 1) {
            OF[(size_t)m * Dm + n] = val;
          } else {
            const int b = m / S, s = m - b * S;
            const int hh = n >> 6, dh = n & 63;
            const ushort bv = f2bf(val);
            if (z < 2)
              OQK[(size_t)z * MD + (((size_t)b * H + hh) * S + s) * DH + dh] = bv;
            else
              OV[(((size_t)b * H + hh) * DH + dh) * SP + s] = bv;
          }
        }
      }
    }
  }
}

// ---------------------------------------------------------------- attention
// one block per (b,h); 4 waves; wave handles q-tiles {w, w+4, w+8, (w==0: 12)}
__global__ __launch_bounds__(256) void attn_fwd(
    const ushort* __restrict__ Qh, const ushort* __restrict__ Kh,
    const ushort* __restrict__ Vt, ushort* __restrict__ xh,
    float* __restrict__ outcls) {
  __shared__ __align__(16) ushort Pl[4][16][232];   // wave-private P exchange
  const int bh = blockIdx.x;
  const int b = bh / H, h = bh - b * H;
  const int tid = threadIdx.x, lane = tid & 63, w = tid >> 6;
  const int rsel = lane & 15, g = lane >> 4;
  const f4 fz = {0.f, 0.f, 0.f, 0.f};

  // zero pad columns 208..231 once (keys 197..207 get exact 0 from masked exp)
#pragma unroll
  for (int t = 0; t < 6; t++) {
    int idx = t * 64 + lane;                 // 0..383 = 16 rows * 24 cols
    Pl[w][idx / 24][208 + idx % 24] = 0;
  }

  const ushort* Qs = Qh + (size_t)bh * S * DH;
  const ushort* Ks = Kh + (size_t)bh * S * DH;
  const ushort* Vs = Vt + (size_t)bh * DH * SP;

  for (int qt = w; qt < 13; qt += 4) {
    const int q0 = qt * 16;
    int qrow = q0 + rsel; if (qrow > S - 1) qrow = S - 1;
    const bf8 aq0 = ld16(Qs + qrow * DH + g * 8);
    const bf8 aq1 = ld16(Qs + qrow * DH + 32 + g * 8);

    // scores: C col = key (lane&15 within tile), row = q (4g+reg)
    f4 sc[13];
#pragma unroll
    for (int kt = 0; kt < 13; kt++) {
      int key = kt * 16 + rsel; if (key > S - 1) key = S - 1;
      const bf8 bk0 = ld16(Ks + key * DH + g * 8);
      const bf8 bk1 = ld16(Ks + key * DH + 32 + g * 8);
      f4 a = fz;
      a = __builtin_amdgcn_mfma_f32_16x16x32_bf16(aq0, bk0, a, 0, 0, 0);
      a = __builtin_amdgcn_mfma_f32_16x16x32_bf16(aq1, bk1, a, 0, 0, 0);
      sc[kt] = a * 0.125f;   // 1/sqrt(64)
    }

    // row softmax: row r of this lane = q0 + 4g + r; reduce over 16 lanes (rsel)
    float mx[4] = {-1e30f, -1e30f, -1e30f, -1e30f};
#pragma unroll
    for (int kt = 0; kt < 13; kt++) {
      const bool vmask = (kt * 16 + rsel) < S;
#pragma unroll
      for (int r = 0; r < 4; r++)
        if (vmask) mx[r] = fmaxf(mx[r], sc[kt][r]);
    }
#pragma unroll
    for (int d = 1; d < 16; d <<= 1)
#pragma unroll
      for (int r = 0; r < 4; r++) mx[r] = fmaxf(mx[r], __shfl_xor(mx[r], d));
    float sm[4] = {0.f, 0.f, 0.f, 0.f};
#pragma unroll
    for (int kt = 0; kt < 13; kt++) {
      const bool vmask = (kt * 16 + rsel) < S;
#pragma unroll
      for (int r = 0; r < 4; r++) {
        const float p = vmask ? exp2f((sc[kt][r] - mx[r]) * 1.44269504f) : 0.f;
        sc[kt][r] = p;
        sm[r] += p;
      }
    }
#pragma unroll
    for (int d = 1; d < 16; d <<= 1)
#pragma unroll
      for (int r = 0; r < 4; r++) sm[r] += __shfl_xor(sm[r], d);

    // CLS attention map: row q==0 lives in reg 0 of lane-group 0
    if (qt == 0 && g == 0) {
      const float inv0 = 1.f / sm[0];
#pragma unroll
      for (int kt = 0; kt < 13; kt++) {
        const int key = kt * 16 + rsel;
        if (key >= 1 && key < S)
          outcls[(size_t)bh * 196 + key - 1] = sc[kt][0] * inv0;
      }
    }

    // P -> LDS (unnormalized, bf16); wave-private so no barrier needed
#pragma unroll
    for (int kt = 0; kt < 13; kt++)
#pragma unroll
      for (int r = 0; r < 4; r++)
        Pl[w][g * 4 + r][kt * 16 + rsel] = f2bf(sc[kt][r]);

    // PV: A = P [16q x 224keys], B = Vt rows (dh-major, key-contiguous)
    bf8 pa[7];
#pragma unroll
    for (int kc = 0; kc < 7; kc++)
      pa[kc] = ld16(&Pl[w][rsel][kc * 32 + g * 8]);
    float inv[4];
#pragma unroll
    for (int r = 0; r < 4; r++) inv[r] = 1.f / sm[r];
#pragma unroll
    for (int nt = 0; nt < 4; nt++) {
      f4 x = fz;
#pragma unroll
      for (int kc = 0; kc < 7; kc++) {
        const bf8 bv = ld16(Vs + (nt * 16 + rsel) * SP + kc * 32 + g * 8);
        x = __builtin_amdgcn_mfma_f32_16x16x32_bf16(pa[kc], bv, x, 0, 0, 0);
      }
#pragma unroll
      for (int r = 0; r < 4; r++) {
        const int s_ = q0 + g * 4 + r;
        if (s_ < S)
          xh[((size_t)b * S + s_) * Dm + h * DH + nt * 16 + rsel] = f2bf(x[r] * inv[r]);
      }
    }
  }
}

// ---------------------------------------------------------------- launch
extern "C" void kernel_launch(void* const* d_in, const int* in_sizes, int n_in,
                              void* d_out, int out_size, void* d_ws, size_t ws_size,
                              hipStream_t stream) {
  (void)in_sizes; (void)n_in; (void)out_size; (void)ws_size;
  const float* q  = (const float*)d_in[0];
  const float* k  = (const float*)d_in[1];
  const float* v  = (const float*)d_in[2];
  const float* wq = (const float*)d_in[3];
  const float* wk = (const float*)d_in[4];
  const float* wv = (const float*)d_in[5];
  const float* wo = (const float*)d_in[6];

  uint8_t* ws = (uint8_t*)d_ws;
  ushort* qb = (ushort*)ws;                 // [M x D] bf16, later reused as xh
  ushort* kb = qb + (size_t)MD;
  ushort* vb = kb + (size_t)MD;
  ushort* wb = vb + (size_t)MD;             // 4 x [768 x 768] bf16
  ushort* Qh = wb + 4 * (size_t)WN;         // [B,H,S,DH] bf16 (then Kh)
  ushort* Kh = Qh + (size_t)MD;
  ushort* Vt = Kh + (size_t)MD;             // [B,H,DH,SP] bf16
  ushort* xh = qb;                          // reuse after projections consumed

  float* out    = (float*)d_out;
  float* outcls = out + (size_t)MD;

  hipMemsetAsync(Vt, 0, (size_t)Bn * H * DH * SP * sizeof(ushort), stream);

  constexpr int CONV_BLOCKS = (3 * (MD / 4) + 4 * (WN / 4)) / 256;  // 30672
  convert_all<<<dim3(CONV_BLOCKS), 256, 0, stream>>>(
      (const float4*)q, (const float4*)k, (const float4*)v,
      (const float4*)wq, (const float4*)wk, (const float4*)wv, (const float4*)wo,
      (ushort4*)qb, (ushort4*)kb, (ushort4*)vb, (ushort4*)wb);

  gemm_bt<0><<<dim3(99, 6, 3), 256, 0, stream>>>(qb, wb, Qh, Vt, nullptr);

  attn_fwd<<<dim3(Bn * H), 256, 0, stream>>>(Qh, Kh, Vt, xh, outcls);

  gemm_bt<1><<<dim3(99, 6, 1), 256, 0, stream>>>(xh, wb + 3 * (size_t)WN, nullptr, nullptr, out);
}

// Round 2
// 331.843 us; speedup vs baseline: 1.0875x; 1.0875x over previous
//
#include <hip/hip_runtime.h>
#include <hip/hip_bf16.h>
#include <stdint.h>

#define DI __device__ __forceinline__

constexpr int Bn = 64;               // batch
constexpr int S  = 197;              // seq
constexpr int Dm = 768;              // model dim
constexpr int H  = 12;               // heads
constexpr int DH = 64;               // head dim
constexpr int M  = Bn * S;           // 12608 rows
constexpr int SP = 224;              // padded seq for transposed V (7 * 32)
constexpr int MD = M * Dm;           // 9,682,944
constexpr int WN = Dm * Dm;          // 589,824
constexpr int NKT = Dm / 64;         // 12 K-tiles of 64

typedef __attribute__((ext_vector_type(8))) short bf8;   // 8 bf16 = 4 VGPRs
typedef __attribute__((ext_vector_type(4))) float f4;

DI ushort f2bf(float f) {
  union { __hip_bfloat16 b; ushort u; } cv;
  cv.b = __float2bfloat16(f);
  return cv.u;
}

// async global->LDS, 16B per lane; lds base must be wave-uniform
DI void gload_lds16(const void* g, const void* lds) {
  __builtin_amdgcn_global_load_lds(
      (__attribute__((address_space(1))) void*)(uintptr_t)g,
      (__attribute__((address_space(3))) void*)(uint32_t)(uintptr_t)lds,
      16, 0, 0);
}

DI bf8 ld16(const ushort* p) { return *(const bf8*)p; }

// counted-vmcnt gates (T4): never drain vmcnt to 0 in the main loop.
// lgkmcnt(0) before the barrier = all waves' ds_reads of the old buffer are
// complete before anyone stages over it (replaces the template's 2nd barrier).
#define GATE4 asm volatile("s_waitcnt vmcnt(4) lgkmcnt(0)\ns_barrier" ::: "memory")
#define GATE0 asm volatile("s_waitcnt vmcnt(0) lgkmcnt(0)\ns_barrier" ::: "memory")

// ---------------------------------------------------------------- convert
__global__ __launch_bounds__(256) void convert_all(
    const float4* __restrict__ q,  const float4* __restrict__ k,
    const float4* __restrict__ v,  const float4* __restrict__ wq,
    const float4* __restrict__ wk, const float4* __restrict__ wv,
    const float4* __restrict__ wo,
    ushort4* __restrict__ qb, ushort4* __restrict__ kb,
    ushort4* __restrict__ vb, ushort4* __restrict__ wb) {
  constexpr int NT = MD / 4;
  constexpr int NW = WN / 4;
  int i = blockIdx.x * 256 + threadIdx.x;
  const float4* src; ushort4* dst; int off;
  if (i < NT)            { src = q; dst = qb; off = i; }
  else if (i < 2 * NT)   { src = k; dst = kb; off = i - NT; }
  else if (i < 3 * NT)   { src = v; dst = vb; off = i - 2 * NT; }
  else {
    int j = i - 3 * NT;
    int wsel = j / NW; off = j - wsel * NW;
    src = wsel == 0 ? wq : wsel == 1 ? wk : wsel == 2 ? wv : wo;
    dst = wb + (size_t)wsel * NW;
  }
  float4 f = src[off];
  ushort4 u;
  u.x = f2bf(f.x); u.y = f2bf(f.y); u.z = f2bf(f.z); u.w = f2bf(f.w);
  dst[off] = u;
}

// ---------------------------------------------------------------- 256^2 pipelined GEMM
// C = A * W^T.  A: [M x 768] bf16 row-major, W: [768 x 768] bf16 ([out][in]).
// 8 waves (2m x 4n), per-wave 128x64 output, BK=64 split as 2 K-halves of 32.
// LDS: 2 dbuf x 2 K-half x 256 rows x 32 k, XOR-swizzled (slot = k8 ^ ((row>>1)&3)).
// Stage 1 half-tile/phase (2 global_load_lds per wave), 4-phase lead,
// vmcnt(4) gates at ph0/ph2 only.

// stage one 256x32 K-half; LDS dest linear, global source pre-swizzled (rule 21)
DI void stage_half(const ushort* __restrict__ src, int rowmax, int row0,
                   int kcol0, ushort* lds_half, int w, int lane) {
#pragma unroll
  for (int l = 0; l < 2; ++l) {
    const int cc = w * 2 + l;                 // wave-uniform chunk id (0..15)
    const int rl = cc * 16 + (lane >> 2);     // row within tile (0..255)
    int rg = row0 + rl; if (rg > rowmax) rg = rowmax;
    const int k8 = (lane & 3) ^ ((rl >> 1) & 3);   // inverse swizzle on source
    gload_lds16(src + (size_t)rg * Dm + kcol0 + k8 * 8, lds_half + cc * 512);
  }
}

// swizzled fragment read: logical 16B chunk g of row -> slot g ^ ((row>>1)&3)
DI bf8 ldfrag(const ushort* half_, int row, int g) {
  return ld16(half_ + row * 32 + ((g ^ ((row >> 1) & 3)) << 3));
}

template <int MODE>
__global__ __launch_bounds__(512, 2) void gemm8(
    const ushort* __restrict__ Abase, const ushort* __restrict__ Wbase,
    ushort* __restrict__ OQK, ushort* __restrict__ OV, float* __restrict__ OF) {
  __shared__ __align__(16) ushort As[2][2][256 * 32];   // 64 KiB
  __shared__ __align__(16) ushort Bs[2][2][256 * 32];   // 64 KiB
  const int tid = threadIdx.x, lane = tid & 63, w = tid >> 6;
  const int wr = w >> 2, wc = w & 3;          // 2 x 4 wave grid
  const int rsel = lane & 15, g = lane >> 4;
  const int n0 = blockIdx.x * 256, m0 = blockIdx.y * 256, z = blockIdx.z;
  const ushort* A = Abase + (MODE == 0 ? (size_t)z * MD : 0);
  const ushort* W = Wbase + (MODE == 0 ? (size_t)z * WN : 0);

  const f4 fz = {0.f, 0.f, 0.f, 0.f};
  f4 acc[8][4];
#pragma unroll
  for (int i = 0; i < 8; i++)
#pragma unroll
    for (int j = 0; j < 4; j++) acc[i][j] = fz;

  // prologue: stage K-tile 0 (4 half-tiles, 8 loads/wave) into buf 0
  stage_half(A, M - 1, m0, 0,  &As[0][0][0], w, lane);
  stage_half(W, 767,   n0, 0,  &Bs[0][0][0], w, lane);
  stage_half(A, M - 1, m0, 32, &As[0][1][0], w, lane);
  stage_half(W, 767,   n0, 32, &Bs[0][1][0], w, lane);

  for (int kt = 0; kt < NKT; ++kt) {
    const int cur = kt & 1, nxt = cur ^ 1;
    const bool pf = kt < NKT - 1;
    const int kc = (kt + 1) * 64;
    bf8 a[4], b[4];

    // ---- ph0: quadrant (i 0-3) x kk=0; publish kt's k0-halves; stage A-k0(kt+1)
    GATE4;
#pragma unroll
    for (int i = 0; i < 4; ++i) a[i] = ldfrag(&As[cur][0][0], wr * 128 + i * 16 + rsel, g);
#pragma unroll
    for (int j = 0; j < 4; ++j) b[j] = ldfrag(&Bs[cur][0][0], wc * 64 + j * 16 + rsel, g);
    if (pf) stage_half(A, M - 1, m0, kc, &As[nxt][0][0], w, lane);
    __builtin_amdgcn_s_setprio(1);
#pragma unroll
    for (int i = 0; i < 4; ++i)
#pragma unroll
      for (int j = 0; j < 4; ++j)
        acc[i][j] = __builtin_amdgcn_mfma_f32_16x16x32_bf16(a[i], b[j], acc[i][j], 0, 0, 0);
    __builtin_amdgcn_s_setprio(0);

    // ---- ph1: quadrant (i 4-7) x kk=0 (B reuse); stage B-k0(kt+1)
#pragma unroll
    for (int i = 0; i < 4; ++i) a[i] = ldfrag(&As[cur][0][0], wr * 128 + (4 + i) * 16 + rsel, g);
    if (pf) stage_half(W, 767, n0, kc, &Bs[nxt][0][0], w, lane);
    __builtin_amdgcn_s_setprio(1);
#pragma unroll
    for (int i = 0; i < 4; ++i)
#pragma unroll
      for (int j = 0; j < 4; ++j)
        acc[4 + i][j] = __builtin_amdgcn_mfma_f32_16x16x32_bf16(a[i], b[j], acc[4 + i][j], 0, 0, 0);
    __builtin_amdgcn_s_setprio(0);

    // ---- ph2: quadrant (i 0-3) x kk=1; publish kt's k1-halves; stage A-k1(kt+1)
    if (kt == NKT - 1) { GATE0; } else { GATE4; }
#pragma unroll
    for (int i = 0; i < 4; ++i) a[i] = ldfrag(&As[cur][1][0], wr * 128 + i * 16 + rsel, g);
#pragma unroll
    for (int j = 0; j < 4; ++j) b[j] = ldfrag(&Bs[cur][1][0], wc * 64 + j * 16 + rsel, g);
    if (pf) stage_half(A, M - 1, m0, kc + 32, &As[nxt][1][0], w, lane);
    __builtin_amdgcn_s_setprio(1);
#pragma unroll
    for (int i = 0; i < 4; ++i)
#pragma unroll
      for (int j = 0; j < 4; ++j)
        acc[i][j] = __builtin_amdgcn_mfma_f32_16x16x32_bf16(a[i], b[j], acc[i][j], 0, 0, 0);
    __builtin_amdgcn_s_setprio(0);

    // ---- ph3: quadrant (i 4-7) x kk=1; stage B-k1(kt+1)
#pragma unroll
    for (int i = 0; i < 4; ++i) a[i] = ldfrag(&As[cur][1][0], wr * 128 + (4 + i) * 16 + rsel, g);
    if (pf) stage_half(W, 767, n0, kc + 32, &Bs[nxt][1][0], w, lane);
    __builtin_amdgcn_s_setprio(1);
#pragma unroll
    for (int i = 0; i < 4; ++i)
#pragma unroll
      for (int j = 0; j < 4; ++j)
        acc[4 + i][j] = __builtin_amdgcn_mfma_f32_16x16x32_bf16(a[i], b[j], acc[4 + i][j], 0, 0, 0);
    __builtin_amdgcn_s_setprio(0);
  }

  // epilogue: C row = (lane>>4)*4+reg (m), col = lane&15 (n)
#pragma unroll
  for (int i = 0; i < 8; i++) {
    const int mb = m0 + wr * 128 + i * 16 + g * 4;
#pragma unroll
    for (int j = 0; j < 4; j++) {
      const int n = n0 + wc * 64 + j * 16 + rsel;
#pragma unroll
      for (int rg = 0; rg < 4; rg++) {
        const int m = mb + rg;
        if (m < M) {
          const float val = acc[i][j][rg];
          if (MODE == 1) {
            OF[(size_t)m * Dm + n] = val;
          } else {
            const int b = m / S, s = m - b * S;
            const int hh = n >> 6, dh = n & 63;
            const ushort bv = f2bf(val);
            if (z < 2)
              OQK[(size_t)z * MD + (((size_t)b * H + hh) * S + s) * DH + dh] = bv;
            else
              OV[(((size_t)b * H + hh) * DH + dh) * SP + s] = bv;
          }
        }
      }
    }
  }
}

// ---------------------------------------------------------------- attention
// one block per (b,h); 4 waves; wave handles q-tiles {w, w+4, w+8, (w==0: 12)}
__global__ __launch_bounds__(256) void attn_fwd(
    const ushort* __restrict__ Qh, const ushort* __restrict__ Kh,
    const ushort* __restrict__ Vt, ushort* __restrict__ xh,
    float* __restrict__ outcls) {
  __shared__ __align__(16) ushort Pl[4][16][232];   // wave-private P exchange
  const int bh = blockIdx.x;
  const int b = bh / H, h = bh - b * H;
  const int tid = threadIdx.x, lane = tid & 63, w = tid >> 6;
  const int rsel = lane & 15, g = lane >> 4;
  const f4 fz = {0.f, 0.f, 0.f, 0.f};

#pragma unroll
  for (int t = 0; t < 6; t++) {
    int idx = t * 64 + lane;                 // zero pad cols 208..231
    Pl[w][idx / 24][208 + idx % 24] = 0;
  }

  const ushort* Qs = Qh + (size_t)bh * S * DH;
  const ushort* Ks = Kh + (size_t)bh * S * DH;
  const ushort* Vs = Vt + (size_t)bh * DH * SP;

  for (int qt = w; qt < 13; qt += 4) {
    const int q0 = qt * 16;
    int qrow = q0 + rsel; if (qrow > S - 1) qrow = S - 1;
    const bf8 aq0 = ld16(Qs + qrow * DH + g * 8);
    const bf8 aq1 = ld16(Qs + qrow * DH + 32 + g * 8);

    f4 sc[13];
#pragma unroll
    for (int kt = 0; kt < 13; kt++) {
      int key = kt * 16 + rsel; if (key > S - 1) key = S - 1;
      const bf8 bk0 = ld16(Ks + key * DH + g * 8);
      const bf8 bk1 = ld16(Ks + key * DH + 32 + g * 8);
      f4 a = fz;
      a = __builtin_amdgcn_mfma_f32_16x16x32_bf16(aq0, bk0, a, 0, 0, 0);
      a = __builtin_amdgcn_mfma_f32_16x16x32_bf16(aq1, bk1, a, 0, 0, 0);
      sc[kt] = a * 0.125f;
    }

    float mx[4] = {-1e30f, -1e30f, -1e30f, -1e30f};
#pragma unroll
    for (int kt = 0; kt < 13; kt++) {
      const bool vmask = (kt * 16 + rsel) < S;
#pragma unroll
      for (int r = 0; r < 4; r++)
        if (vmask) mx[r] = fmaxf(mx[r], sc[kt][r]);
    }
#pragma unroll
    for (int d = 1; d < 16; d <<= 1)
#pragma unroll
      for (int r = 0; r < 4; r++) mx[r] = fmaxf(mx[r], __shfl_xor(mx[r], d));
    float sm[4] = {0.f, 0.f, 0.f, 0.f};
#pragma unroll
    for (int kt = 0; kt < 13; kt++) {
      const bool vmask = (kt * 16 + rsel) < S;
#pragma unroll
      for (int r = 0; r < 4; r++) {
        const float p = vmask ? exp2f((sc[kt][r] - mx[r]) * 1.44269504f) : 0.f;
        sc[kt][r] = p;
        sm[r] += p;
      }
    }
#pragma unroll
    for (int d = 1; d < 16; d <<= 1)
#pragma unroll
      for (int r = 0; r < 4; r++) sm[r] += __shfl_xor(sm[r], d);

    if (qt == 0 && g == 0) {
      const float inv0 = 1.f / sm[0];
#pragma unroll
      for (int kt = 0; kt < 13; kt++) {
        const int key = kt * 16 + rsel;
        if (key >= 1 && key < S)
          outcls[(size_t)bh * 196 + key - 1] = sc[kt][0] * inv0;
      }
    }

#pragma unroll
    for (int kt = 0; kt < 13; kt++)
#pragma unroll
      for (int r = 0; r < 4; r++)
        Pl[w][g * 4 + r][kt * 16 + rsel] = f2bf(sc[kt][r]);

    bf8 pa[7];
#pragma unroll
    for (int kc = 0; kc < 7; kc++)
      pa[kc] = ld16(&Pl[w][rsel][kc * 32 + g * 8]);
    float inv[4];
#pragma unroll
    for (int r = 0; r < 4; r++) inv[r] = 1.f / sm[r];
#pragma unroll
    for (int nt = 0; nt < 4; nt++) {
      f4 x = fz;
#pragma unroll
      for (int kc = 0; kc < 7; kc++) {
        const bf8 bv = ld16(Vs + (nt * 16 + rsel) * SP + kc * 32 + g * 8);
        x = __builtin_amdgcn_mfma_f32_16x16x32_bf16(pa[kc], bv, x, 0, 0, 0);
      }
#pragma unroll
      for (int r = 0; r < 4; r++) {
        const int s_ = q0 + g * 4 + r;
        if (s_ < S)
          xh[((size_t)b * S + s_) * Dm + h * DH + nt * 16 + rsel] = f2bf(x[r] * inv[r]);
      }
    }
  }
}

// ---------------------------------------------------------------- launch
extern "C" void kernel_launch(void* const* d_in, const int* in_sizes, int n_in,
                              void* d_out, int out_size, void* d_ws, size_t ws_size,
                              hipStream_t stream) {
  (void)in_sizes; (void)n_in; (void)out_size; (void)ws_size;
  const float* q  = (const float*)d_in[0];
  const float* k  = (const float*)d_in[1];
  const float* v  = (const float*)d_in[2];
  const float* wq = (const float*)d_in[3];
  const float* wk = (const float*)d_in[4];
  const float* wv = (const float*)d_in[5];
  const float* wo = (const float*)d_in[6];

  uint8_t* ws = (uint8_t*)d_ws;
  ushort* qb = (ushort*)ws;                 // [M x D] bf16, later reused as xh
  ushort* kb = qb + (size_t)MD;
  ushort* vb = kb + (size_t)MD;
  ushort* wb = vb + (size_t)MD;             // 4 x [768 x 768] bf16
  ushort* Qh = wb + 4 * (size_t)WN;         // [B,H,S,DH] bf16 (then Kh)
  ushort* Kh = Qh + (size_t)MD;
  ushort* Vt = Kh + (size_t)MD;             // [B,H,DH,SP] bf16
  ushort* xh = qb;                          // reuse after projections consumed

  float* out    = (float*)d_out;
  float* outcls = out + (size_t)MD;

  hipMemsetAsync(Vt, 0, (size_t)Bn * H * DH * SP * sizeof(ushort), stream);

  constexpr int CONV_BLOCKS = (3 * (MD / 4) + 4 * (WN / 4)) / 256;
  convert_all<<<dim3(CONV_BLOCKS), 256, 0, stream>>>(
      (const float4*)q, (const float4*)k, (const float4*)v,
      (const float4*)wq, (const float4*)wk, (const float4*)wv, (const float4*)wo,
      (ushort4*)qb, (ushort4*)kb, (ushort4*)vb, (ushort4*)wb);

  // x = n-tile (3) fastest so consecutive blocks share the A panel in L2
  gemm8<0><<<dim3(3, 50, 3), 512, 0, stream>>>(qb, wb, Qh, Vt, nullptr);

  attn_fwd<<<dim3(Bn * H), 256, 0, stream>>>(Qh, Kh, Vt, xh, outcls);

  gemm8<1><<<dim3(3, 50, 1), 512, 0, stream>>>(xh, wb + 3 * (size_t)WN, nullptr, nullptr, out);
}

// Round 3
// 318.520 us; speedup vs baseline: 1.1330x; 1.0418x over previous
//
#include <hip/hip_runtime.h>
#include <hip/hip_bf16.h>
#include <stdint.h>

#define DI __device__ __forceinline__

constexpr int Bn = 64;               // batch
constexpr int S  = 197;              // seq
constexpr int Dm = 768;              // model dim
constexpr int H  = 12;               // heads
constexpr int DH = 64;               // head dim
constexpr int M  = Bn * S;           // 12608 rows
constexpr int SP = 224;              // padded seq for transposed V (7 * 32)
constexpr int MD = M * Dm;           // 9,682,944
constexpr int WN = Dm * Dm;          // 589,824

typedef __attribute__((ext_vector_type(8))) short bf8;   // 8 bf16 = 4 VGPRs
typedef __attribute__((ext_vector_type(4))) float f4;

DI ushort f2bf(float f) {
  union { __hip_bfloat16 b; ushort u; } cv;
  cv.b = __float2bfloat16(f);
  return cv.u;
}

// async global->LDS, 16B per lane; lds base must be wave-uniform
DI void gload_lds16(const void* g, const void* lds) {
  __builtin_amdgcn_global_load_lds(
      (__attribute__((address_space(1))) void*)(uintptr_t)g,
      (__attribute__((address_space(3))) void*)(uint32_t)(uintptr_t)lds,
      16, 0, 0);
}

DI bf8 ld16(const ushort* p) { return *(const bf8*)p; }

// ---------------------------------------------------------------- convert
__global__ __launch_bounds__(256) void convert_all(
    const float4* __restrict__ q,  const float4* __restrict__ k,
    const float4* __restrict__ v,  const float4* __restrict__ wq,
    const float4* __restrict__ wk, const float4* __restrict__ wv,
    const float4* __restrict__ wo,
    ushort4* __restrict__ qb, ushort4* __restrict__ kb,
    ushort4* __restrict__ vb, ushort4* __restrict__ wb) {
  constexpr int NT = MD / 4;
  constexpr int NW = WN / 4;
  int i = blockIdx.x * 256 + threadIdx.x;
  const float4* src; ushort4* dst; int off;
  if (i < NT)            { src = q; dst = qb; off = i; }
  else if (i < 2 * NT)   { src = k; dst = kb; off = i - NT; }
  else if (i < 3 * NT)   { src = v; dst = vb; off = i - 2 * NT; }
  else {
    int j = i - 3 * NT;
    int wsel = j / NW; off = j - wsel * NW;
    src = wsel == 0 ? wq : wsel == 1 ? wk : wsel == 2 ? wv : wo;
    dst = wb + (size_t)wsel * NW;
  }
  float4 f = src[off];
  ushort4 u;
  u.x = f2bf(f.x); u.y = f2bf(f.y); u.z = f2bf(f.z); u.w = f2bf(f.w);
  dst[off] = u;
}

// ---------------------------------------------------------------- 128^2 GEMM (m97-class)
// C = A * W^T.  A: [M x 768] bf16 row-major, W: [768 x 768] bf16 ([out][in]).
// 4 waves (2x2), per-wave 64x64 output, BK=32, double-buffered LDS (32 KiB),
// XOR-swizzled (slot = g ^ ((row>>1)&3)), one vmcnt(0)+lgkmcnt(0)+barrier
// gate per K-step. 3 blocks/CU via __launch_bounds__(256,3).

// stage one 128x32 slab; LDS dest linear, global source pre-swizzled (rule 21)
DI void stage128(const ushort* __restrict__ src, int rowmax, int row0,
                 int kcol0, ushort* lds, int w, int lane) {
#pragma unroll
  for (int l = 0; l < 2; ++l) {
    const int cid = w * 2 + l;            // wave-uniform 0..7
    const int c = cid * 64 + lane;        // chunk 0..511 (4 chunks of 16B/row)
    const int rl = c >> 2;
    int rg = row0 + rl; if (rg > rowmax) rg = rowmax;
    const int k8 = (c & 3) ^ ((rl >> 1) & 3);   // inverse swizzle on source
    gload_lds16(src + (size_t)rg * Dm + kcol0 + k8 * 8, lds + cid * 512);
  }
}

// swizzled fragment read: logical 16B chunk g of row -> slot g ^ ((row>>1)&3)
DI bf8 ldfrag(const ushort* buf, int row, int g) {
  return ld16(buf + row * 32 + ((g ^ ((row >> 1) & 3)) << 3));
}

#define KSTEP(KT, CUR, NXT)                                               \
  {                                                                       \
    if ((KT) < 23) {                                                      \
      stage128(A, M - 1, m0, ((KT) + 1) * 32, As[NXT], w, lane);          \
      stage128(W, 767, n0, ((KT) + 1) * 32, Bs[NXT], w, lane);            \
    }                                                                     \
    bf8 a[4], b[4];                                                       \
    _Pragma("unroll") for (int i = 0; i < 4; ++i)                         \
        a[i] = ldfrag(As[CUR], wr * 64 + i * 16 + rsel, g);               \
    _Pragma("unroll") for (int j = 0; j < 4; ++j)                         \
        b[j] = ldfrag(Bs[CUR], wc * 64 + j * 16 + rsel, g);               \
    __builtin_amdgcn_s_setprio(1);                                        \
    _Pragma("unroll") for (int i = 0; i < 4; ++i)                         \
      _Pragma("unroll") for (int j = 0; j < 4; ++j)                       \
        acc[i][j] = __builtin_amdgcn_mfma_f32_16x16x32_bf16(              \
            a[i], b[j], acc[i][j], 0, 0, 0);                              \
    __builtin_amdgcn_s_setprio(0);                                        \
    asm volatile("s_waitcnt vmcnt(0) lgkmcnt(0)" ::: "memory");           \
    __builtin_amdgcn_s_barrier();                                         \
  }

template <int MODE>
__global__ __launch_bounds__(256, 3) void gemmL(
    const ushort* __restrict__ Ab, const ushort* __restrict__ Wb,
    ushort* __restrict__ OQK, ushort* __restrict__ OV, float* __restrict__ OF) {
  __shared__ __align__(16) ushort As[2][128 * 32];   // 16 KiB
  __shared__ __align__(16) ushort Bs[2][128 * 32];   // 16 KiB
  constexpr int NT  = 6;       // n-tiles (N = 768)
  constexpr int NWG = 594;     // 99 m-tiles * 6 n-tiles
  const int tid = threadIdx.x, lane = tid & 63, w = tid >> 6;
  const int wr = w >> 1, wc = w & 1;
  const int rsel = lane & 15, g = lane >> 4;

  // bijective XCD swizzle (m204), n-fastest for A-panel L2 reuse
  constexpr int qq = NWG / 8, rr = NWG % 8;
  const int bid = blockIdx.x;
  const int xcd = bid & 7, pos = bid >> 3;
  const int wg = (xcd < rr ? xcd * (qq + 1) : rr * (qq + 1) + (xcd - rr) * qq) + pos;
  const int nt = wg % NT, mt = wg / NT;
  const int n0 = nt * 128, m0 = mt * 128;
  const int z = blockIdx.y;
  const ushort* A = Ab + (size_t)z * MD;
  const ushort* W = Wb + (size_t)z * WN;

  const f4 fz = {0.f, 0.f, 0.f, 0.f};
  f4 acc[4][4];
#pragma unroll
  for (int i = 0; i < 4; i++)
#pragma unroll
    for (int j = 0; j < 4; j++) acc[i][j] = fz;

  stage128(A, M - 1, m0, 0, As[0], w, lane);
  stage128(W, 767, n0, 0, Bs[0], w, lane);
  asm volatile("s_waitcnt vmcnt(0)" ::: "memory");
  __builtin_amdgcn_s_barrier();

#pragma unroll 1
  for (int kt2 = 0; kt2 < 12; ++kt2) {
    const int kt = kt2 * 2;
    KSTEP(kt, 0, 1);
    KSTEP(kt + 1, 1, 0);
  }

  // epilogue: C row = (lane>>4)*4+reg (m), col = lane&15 (n)
#pragma unroll
  for (int i = 0; i < 4; i++) {
    const int mb = m0 + wr * 64 + i * 16 + g * 4;
#pragma unroll
    for (int j = 0; j < 4; j++) {
      const int n = n0 + wc * 64 + j * 16 + rsel;
#pragma unroll
      for (int rg = 0; rg < 4; rg++) {
        const int m = mb + rg;
        if (m < M) {
          const float val = acc[i][j][rg];
          if (MODE == 1) {
            OF[(size_t)m * Dm + n] = val;
          } else {
            const int b = m / S, s = m - b * S;
            const int hh = n >> 6, dh = n & 63;
            const ushort bv = f2bf(val);
            if (z < 2)
              OQK[(size_t)z * MD + (((size_t)b * H + hh) * S + s) * DH + dh] = bv;
            else
              OV[(((size_t)b * H + hh) * DH + dh) * SP + s] = bv;
          }
        }
      }
    }
  }
}

// ---------------------------------------------------------------- attention
// one block per (b,h); 4 waves; wave handles q-tiles {w, w+4, w+8, (w==0: 12)}
__global__ __launch_bounds__(256) void attn_fwd(
    const ushort* __restrict__ Qh, const ushort* __restrict__ Kh,
    const ushort* __restrict__ Vt, ushort* __restrict__ xh,
    float* __restrict__ outcls) {
  __shared__ __align__(16) ushort Pl[4][16][232];   // wave-private P exchange
  const int bh = blockIdx.x;
  const int b = bh / H, h = bh - b * H;
  const int tid = threadIdx.x, lane = tid & 63, w = tid >> 6;
  const int rsel = lane & 15, g = lane >> 4;
  const f4 fz = {0.f, 0.f, 0.f, 0.f};

#pragma unroll
  for (int t = 0; t < 6; t++) {
    int idx = t * 64 + lane;                 // zero pad cols 208..231
    Pl[w][idx / 24][208 + idx % 24] = 0;
  }

  const ushort* Qs = Qh + (size_t)bh * S * DH;
  const ushort* Ks = Kh + (size_t)bh * S * DH;
  const ushort* Vs = Vt + (size_t)bh * DH * SP;

  for (int qt = w; qt < 13; qt += 4) {
    const int q0 = qt * 16;
    int qrow = q0 + rsel; if (qrow > S - 1) qrow = S - 1;
    const bf8 aq0 = ld16(Qs + qrow * DH + g * 8);
    const bf8 aq1 = ld16(Qs + qrow * DH + 32 + g * 8);

    f4 sc[13];
#pragma unroll
    for (int kt = 0; kt < 13; kt++) {
      int key = kt * 16 + rsel; if (key > S - 1) key = S - 1;
      const bf8 bk0 = ld16(Ks + key * DH + g * 8);
      const bf8 bk1 = ld16(Ks + key * DH + 32 + g * 8);
      f4 a = fz;
      a = __builtin_amdgcn_mfma_f32_16x16x32_bf16(aq0, bk0, a, 0, 0, 0);
      a = __builtin_amdgcn_mfma_f32_16x16x32_bf16(aq1, bk1, a, 0, 0, 0);
      sc[kt] = a * 0.125f;
    }

    float mx[4] = {-1e30f, -1e30f, -1e30f, -1e30f};
#pragma unroll
    for (int kt = 0; kt < 13; kt++) {
      const bool vmask = (kt * 16 + rsel) < S;
#pragma unroll
      for (int r = 0; r < 4; r++)
        if (vmask) mx[r] = fmaxf(mx[r], sc[kt][r]);
    }
#pragma unroll
    for (int d = 1; d < 16; d <<= 1)
#pragma unroll
      for (int r = 0; r < 4; r++) mx[r] = fmaxf(mx[r], __shfl_xor(mx[r], d));
    float sm[4] = {0.f, 0.f, 0.f, 0.f};
#pragma unroll
    for (int kt = 0; kt < 13; kt++) {
      const bool vmask = (kt * 16 + rsel) < S;
#pragma unroll
      for (int r = 0; r < 4; r++) {
        const float p = vmask ? exp2f((sc[kt][r] - mx[r]) * 1.44269504f) : 0.f;
        sc[kt][r] = p;
        sm[r] += p;
      }
    }
#pragma unroll
    for (int d = 1; d < 16; d <<= 1)
#pragma unroll
      for (int r = 0; r < 4; r++) sm[r] += __shfl_xor(sm[r], d);

    if (qt == 0 && g == 0) {
      const float inv0 = 1.f / sm[0];
#pragma unroll
      for (int kt = 0; kt < 13; kt++) {
        const int key = kt * 16 + rsel;
        if (key >= 1 && key < S)
          outcls[(size_t)bh * 196 + key - 1] = sc[kt][0] * inv0;
      }
    }

#pragma unroll
    for (int kt = 0; kt < 13; kt++)
#pragma unroll
      for (int r = 0; r < 4; r++)
        Pl[w][g * 4 + r][kt * 16 + rsel] = f2bf(sc[kt][r]);

    bf8 pa[7];
#pragma unroll
    for (int kc = 0; kc < 7; kc++)
      pa[kc] = ld16(&Pl[w][rsel][kc * 32 + g * 8]);
    float inv[4];
#pragma unroll
    for (int r = 0; r < 4; r++) inv[r] = 1.f / sm[r];
#pragma unroll
    for (int nt = 0; nt < 4; nt++) {
      f4 x = fz;
#pragma unroll
      for (int kc = 0; kc < 7; kc++) {
        const bf8 bv = ld16(Vs + (nt * 16 + rsel) * SP + kc * 32 + g * 8);
        x = __builtin_amdgcn_mfma_f32_16x16x32_bf16(pa[kc], bv, x, 0, 0, 0);
      }
#pragma unroll
      for (int r = 0; r < 4; r++) {
        const int s_ = q0 + g * 4 + r;
        if (s_ < S)
          xh[((size_t)b * S + s_) * Dm + h * DH + nt * 16 + rsel] = f2bf(x[r] * inv[r]);
      }
    }
  }
}

// ---------------------------------------------------------------- launch
extern "C" void kernel_launch(void* const* d_in, const int* in_sizes, int n_in,
                              void* d_out, int out_size, void* d_ws, size_t ws_size,
                              hipStream_t stream) {
  (void)in_sizes; (void)n_in; (void)out_size; (void)ws_size;
  const float* q  = (const float*)d_in[0];
  const float* k  = (const float*)d_in[1];
  const float* v  = (const float*)d_in[2];
  const float* wq = (const float*)d_in[3];
  const float* wk = (const float*)d_in[4];
  const float* wv = (const float*)d_in[5];
  const float* wo = (const float*)d_in[6];

  uint8_t* ws = (uint8_t*)d_ws;
  ushort* qb = (ushort*)ws;                 // [M x D] bf16, later reused as xh
  ushort* kb = qb + (size_t)MD;
  ushort* vb = kb + (size_t)MD;
  ushort* wb = vb + (size_t)MD;             // 4 x [768 x 768] bf16
  ushort* Qh = wb + 4 * (size_t)WN;         // [B,H,S,DH] bf16 (then Kh)
  ushort* Kh = Qh + (size_t)MD;
  ushort* Vt = Kh + (size_t)MD;             // [B,H,DH,SP] bf16
  ushort* xh = qb;                          // reuse after projections consumed

  float* out    = (float*)d_out;
  float* outcls = out + (size_t)MD;

  hipMemsetAsync(Vt, 0, (size_t)Bn * H * DH * SP * sizeof(ushort), stream);

  constexpr int CONV_BLOCKS = (3 * (MD / 4) + 4 * (WN / 4)) / 256;
  convert_all<<<dim3(CONV_BLOCKS), 256, 0, stream>>>(
      (const float4*)q, (const float4*)k, (const float4*)v,
      (const float4*)wq, (const float4*)wk, (const float4*)wv, (const float4*)wo,
      (ushort4*)qb, (ushort4*)kb, (ushort4*)vb, (ushort4*)wb);

  gemmL<0><<<dim3(594, 3), 256, 0, stream>>>(qb, wb, Qh, Vt, nullptr);

  attn_fwd<<<dim3(Bn * H), 256, 0, stream>>>(Qh, Kh, Vt, xh, outcls);

  gemmL<1><<<dim3(594, 1), 256, 0, stream>>>(xh, wb + 3 * (size_t)WN, nullptr, nullptr, out);
}